// Round 10
// baseline (99.620 us; speedup 1.0000x reference)
//
#include <hip/hip_runtime.h>

typedef long long i64;
typedef unsigned long long u64;

// ---------------------------------------------------------------------------
// Established facts (R1-R9):
//  - int64 inputs; int32 output [total*3] neg then [total] keep.
//  - R4/R8 bsearch: 53 us. R8 broadcast-tail NEUTRAL => not BW-bound; bound
//    by VALU + dependent-load chain depth.
//  - R9 interpolation search (chain 20 -> ~4): kernel ~26 us (bench 123->97),
//    matched prediction. Remaining: ~600 cyc serial probe chain per thread,
//    stride-12B scattered stores. Write roofline floor ~12 us.
// This round: 4 samples/thread. Four independent interp searches advanced in
// LOCKSTEP (4 loads in flight per level -> exposed latency /4 per sample),
// pos triple loaded once per thread, outputs packed into int4 stores.
// Same proven shell: ONE dispatch, width probe, no d_ws/atomics/cross-lane.
// ---------------------------------------------------------------------------

template <typename T>
__device__ __forceinline__ bool interp_member(const T* __restrict__ table,
                                              int L, u64 key) {
    u64 v0 = (u64)table[0];
    u64 vN = (u64)table[L - 1];
    if (key <= v0) return key == v0;
    if (key >= vN) return key == vN;
    int lo = 0, hi = L - 1;
    u64 vlo = v0, vhi = vN;
    for (int it = 0; it < 12 && hi - lo > 8; ++it) {
        float f = (float)(key - vlo) * __builtin_amdgcn_rcpf((float)(vhi - vlo));
        int mid = lo + (int)(f * (float)(hi - lo));
        if (mid <= lo) mid = lo + 1;
        if (mid >= hi) mid = hi - 1;
        u64 v = (u64)table[mid];
        if (v == key) return true;
        if (v < key) { lo = mid; vlo = v; }
        else         { hi = mid; vhi = v; }
    }
    while (hi - lo > 8) {
        int mid = lo + ((hi - lo) >> 1);
        u64 v = (u64)table[mid];
        if (v == key) return true;
        if (v < key) lo = mid; else hi = mid;
    }
    bool eq = false;
    for (int j = lo + 1; j < hi; ++j) eq |= ((u64)table[j] == key);
    return eq;
}

// Four membership queries in lockstep: per level, up to 4 independent loads
// are in flight under a single waitcnt, then all states advance.
template <typename T>
__device__ __forceinline__ void interp_member4(const T* __restrict__ table,
                                               int L, const u64* key, bool* res) {
    u64 v0 = (u64)table[0];
    u64 vN = (u64)table[L - 1];
    int lo[4], hi[4];
    u64 vlo[4], vhi[4];
    bool done[4];
#pragma unroll
    for (int k = 0; k < 4; ++k) {
        res[k] = false; done[k] = false;
        lo[k] = 0; hi[k] = L - 1; vlo[k] = v0; vhi[k] = vN;
        if (key[k] <= v0)      { res[k] = (key[k] == v0); done[k] = true; }
        else if (key[k] >= vN) { res[k] = (key[k] == vN); done[k] = true; }
    }
    for (int it = 0; it < 12; ++it) {
        bool act[4]; int mid[4]; u64 v[4];
        bool any = false;
#pragma unroll
        for (int k = 0; k < 4; ++k) {
            act[k] = !done[k] && (hi[k] - lo[k] > 8);
            if (act[k]) {
                float f = (float)(key[k] - vlo[k]) *
                          __builtin_amdgcn_rcpf((float)(vhi[k] - vlo[k]));
                int m = lo[k] + (int)(f * (float)(hi[k] - lo[k]));
                if (m <= lo[k]) m = lo[k] + 1;
                if (m >= hi[k]) m = hi[k] - 1;
                mid[k] = m;
                v[k] = (u64)table[m];          // 4 independent probes in flight
                any = true;
            }
        }
#pragma unroll
        for (int k = 0; k < 4; ++k) {
            if (!act[k]) continue;
            if (v[k] == key[k])     { res[k] = true; done[k] = true; }
            else if (v[k] < key[k]) { lo[k] = mid[k]; vlo[k] = v[k]; }
            else                    { hi[k] = mid[k]; vhi[k] = v[k]; }
        }
        if (!any) break;
    }
#pragma unroll
    for (int k = 0; k < 4; ++k) {
        if (done[k]) continue;
        while (hi[k] - lo[k] > 8) {            // fallback; w.h.p. never runs
            int m = lo[k] + ((hi[k] - lo[k]) >> 1);
            u64 v = (u64)table[m];
            if (v == key[k]) { res[k] = true; done[k] = true; break; }
            if (v < key[k]) lo[k] = m; else hi[k] = m;
        }
        if (done[k]) continue;
        bool eq = false;                       // <=7 independent loads
        for (int j = lo[k] + 1; j < hi[k]; ++j) eq |= ((u64)table[j] == key[k]);
        res[k] = eq;
    }
}

template <typename T>
__device__ __forceinline__ void sample_body4(
    const T* __restrict__ pos, const T* __restrict__ rand_vals,
    const T* __restrict__ table,
    int* __restrict__ out_neg, int* __restrict__ out_keep,
    unsigned j, int split, int L, unsigned num_negs)
{
    const unsigned s0 = j * 4u;
    const unsigned b = s0 / num_negs;   // all 4 samples share b (num_negs%4==0)
    i64 ph = (i64)pos[3 * b + 0];
    i64 pr = (i64)pos[3 * b + 1];
    i64 pt = (i64)pos[3 * b + 2];

    u64 key[4]; int hh[4], tt[4];
#pragma unroll
    for (int k = 0; k < 4; ++k) {
        unsigned s = s0 + k;
        i64 h = ph, t = pt;
        i64 rv = (i64)rand_vals[s];
        const bool corrupt_head = (s < (unsigned)split);
        i64 orig = corrupt_head ? h : t;
        i64 repl = rv + (((rv >= orig) & (orig > 0)) ? 1 : 0);
        if (corrupt_head) h = repl; else t = repl;
        key[k] = ((u64)h << 42) | ((u64)pr << 21) | (u64)t;
        hh[k] = (int)h; tt[k] = (int)t;
    }

    bool in_set[4];
    interp_member4(table, L, key, in_set);

    const int rr = (int)pr;
    int4* on = (int4*)(out_neg + (size_t)s0 * 3);     // 48B-aligned
    on[0] = make_int4(hh[0], rr, tt[0], hh[1]);
    on[1] = make_int4(rr, tt[1], hh[2], rr);
    on[2] = make_int4(tt[2], hh[3], rr, tt[3]);
    *(int4*)(out_keep + s0) = make_int4(in_set[0] ? 0 : 1, in_set[1] ? 0 : 1,
                                        in_set[2] ? 0 : 1, in_set[3] ? 0 : 1);
}

__global__ __launch_bounds__(256) void neg_sample_x4(
    const void* __restrict__ pos, const void* __restrict__ rand_vals,
    const void* __restrict__ table,
    int* __restrict__ out_neg, int* __restrict__ out_keep,
    int nthreads, int split, int L, unsigned num_negs)
{
    unsigned j = blockIdx.x * blockDim.x + threadIdx.x;
    if (j >= (unsigned)nthreads) return;

    // Width probe (R2-proven): pos int32-view word 3 == 0 iff int64 storage.
    const int* pw = (const int*)pos;
    const bool is64 = (pw[3] == 0);   // wave-uniform, L1-hot

    if (is64) {
        sample_body4<i64>((const i64*)pos, (const i64*)rand_vals, (const i64*)table,
                          out_neg, out_keep, j, split, L, num_negs);
    } else {
        sample_body4<int>((const int*)pos, (const int*)rand_vals, (const int*)table,
                          out_neg, out_keep, j, split, L, num_negs);
    }
}

// Generic fallback: R9's proven scalar kernel (any shape).
template <typename T>
__device__ __forceinline__ void sample_body1(
    const T* __restrict__ pos, const T* __restrict__ rand_vals,
    const T* __restrict__ table,
    int* __restrict__ out_neg, int* __restrict__ out_keep,
    unsigned i, int split, int L, unsigned num_negs)
{
    unsigned b = i / num_negs;
    i64 h = (i64)pos[3 * b + 0];
    i64 r = (i64)pos[3 * b + 1];
    i64 t = (i64)pos[3 * b + 2];
    i64 rv = (i64)rand_vals[i];
    const bool corrupt_head = (i < (unsigned)split);
    i64 orig = corrupt_head ? h : t;
    i64 repl = rv + (((rv >= orig) & (orig > 0)) ? 1 : 0);
    if (corrupt_head) h = repl; else t = repl;
    u64 key = ((u64)h << 42) | ((u64)r << 21) | (u64)t;
    bool in_set = interp_member(table, L, key);
    out_neg[3 * (size_t)i + 0] = (int)h;
    out_neg[3 * (size_t)i + 1] = (int)r;
    out_neg[3 * (size_t)i + 2] = (int)t;
    out_keep[i] = in_set ? 0 : 1;
}

__global__ __launch_bounds__(256) void neg_sample_x1(
    const void* __restrict__ pos, const void* __restrict__ rand_vals,
    const void* __restrict__ table,
    int* __restrict__ out_neg, int* __restrict__ out_keep,
    int total, int split, int L, unsigned num_negs)
{
    unsigned i = blockIdx.x * blockDim.x + threadIdx.x;
    if (i >= (unsigned)total) return;
    const int* pw = (const int*)pos;
    const bool is64 = (pw[3] == 0);
    if (is64) {
        sample_body1<i64>((const i64*)pos, (const i64*)rand_vals, (const i64*)table,
                          out_neg, out_keep, i, split, L, num_negs);
    } else {
        sample_body1<int>((const int*)pos, (const int*)rand_vals, (const int*)table,
                          out_neg, out_keep, i, split, L, num_negs);
    }
}

extern "C" void kernel_launch(void* const* d_in, const int* in_sizes, int n_in,
                              void* d_out, int out_size, void* d_ws, size_t ws_size,
                              hipStream_t stream) {
    const void* pos       = d_in[0];
    const void* rand_vals = d_in[1];
    const void* table     = d_in[2];

    const int B     = in_sizes[0] / 3;
    const int total = in_sizes[1];
    const int L     = in_sizes[2];
    const unsigned num_negs = (unsigned)(total / B);
    const int split = (total + 1) / 2;   // ceil(total/2)

    int* out_neg  = (int*)d_out;
    int* out_keep = out_neg + (size_t)total * 3;

    const int threads = 256;

    // x4 path needs: 4-groups never straddle a positive (num_negs%4==0),
    // exact thread cover (total%4==0). Corrupt-side handled per-sample.
    if (total % 4 == 0 && num_negs % 4u == 0u) {
        const int nthreads = total / 4;
        const int blocks = (nthreads + threads - 1) / threads;
        neg_sample_x4<<<blocks, threads, 0, stream>>>(
            pos, rand_vals, table, out_neg, out_keep, nthreads, split, L, num_negs);
    } else {
        const int blocks = (total + threads - 1) / threads;
        neg_sample_x1<<<blocks, threads, 0, stream>>>(
            pos, rand_vals, table, out_neg, out_keep, total, split, L, num_negs);
    }
}